// Round 15
// baseline (101.744 us; speedup 1.0000x reference)
//
#include <hip/hip_runtime.h>

typedef unsigned short u16;
typedef unsigned int u32;

#define B_   4
#define C_   256
#define CI_  128
#define H_   64
#define W_   64
#define NPB_ 4096     // pixels per batch image
#define NP_  16384    // total pixels
#define K_   9        // 3x3 taps
#define MROWS_ 272    // 128 q + 128 k + 1 wcomb + 15 pad

// k2 tile geometry
#define TH_  4
#define TW_  8
#define WH_  16       // window rows  (TH + 2*6)
#define WW_  20       // window cols  (TW + 2*6)
#define WPX_ (WH_ * WW_)   // 320
#define CROW_ 68      // u16 stride per window pixel in chunk buffer (bank-rotating)

typedef __attribute__((ext_vector_type(8))) __bf16 bf16x8_t;
typedef __attribute__((ext_vector_type(4))) float f32x4_t;
typedef __attribute__((ext_vector_type(2))) float f32x2_t;
typedef __attribute__((ext_vector_type(4))) u32 u32x4;

// forced-issue global load (k1): volatile asm order is preserved.
#define GLD(dst, p, immstr) \
    asm volatile("global_load_dwordx4 %0, %1, off offset:" immstr \
                 : "=v"(dst) : "v"(p))

__device__ __forceinline__ float bf2f_lo(u32 w) {
    union { u32 i; float f; } x; x.i = w << 16; return x.f;
}
__device__ __forceinline__ float bf2f_hi(u32 w) {
    union { u32 i; float f; } x; x.i = w & 0xffff0000u; return x.f;
}
__device__ __forceinline__ u16 f2bf(float f) {  // round-to-nearest-even
    union { float f; u32 i; } x; x.f = f;
    u32 lsb = (x.i >> 16) & 1u;
    return (u16)((x.i + 0x7fffu + lsb) >> 16);
}
// packed bilinear accumulate: 8 bf16 channels, f32x2 lanes -> v_pk_fma_f32
__device__ __forceinline__ void acc8p(f32x2_t* f, u32x4 v, f32x2_t w2) {
    f32x2_t p;
    p.x = bf2f_lo(v[0]); p.y = bf2f_hi(v[0]); f[0] += w2 * p;
    p.x = bf2f_lo(v[1]); p.y = bf2f_hi(v[1]); f[1] += w2 * p;
    p.x = bf2f_lo(v[2]); p.y = bf2f_hi(v[2]); f[2] += w2 * p;
    p.x = bf2f_lo(v[3]); p.y = bf2f_hi(v[3]); f[3] += w2 * p;
}

// k0b: prepare Wt in FRAGMENT-TILED layout + bias[272]. (unchanged)
__global__ void k0b_prep(const float* __restrict__ Wq, const float* __restrict__ bq,
                         const float* __restrict__ Wk, const float* __restrict__ bk,
                         const float* __restrict__ Wv, const float* __restrict__ bv,
                         const float* __restrict__ Wo,
                         u16* __restrict__ Wt, float* __restrict__ bias) {
    const int o = blockIdx.x;   // 0..271 (row)
    const int c = threadIdx.x;  // 0..255 (channel)
    u16 val;
    if (o < 128) {
        val = f2bf(Wq[o * C_ + c]);
        if (c == 0) bias[o] = bq[o];
    } else if (o < 256) {
        val = f2bf(Wk[(o - 128) * C_ + c]);
        if (c == 0) bias[o] = bk[o - 128];
    } else if (o == 256) {
        float s = 0.f;
        #pragma unroll 8
        for (int oo = 0; oo < CI_; ++oo)
            s += Wo[oo] * Wv[oo * C_ + c];
        val = f2bf(s);
        if (c == 0) {
            float ts = 0.f;
            #pragma unroll 8
            for (int oo = 0; oo < CI_; ++oo) ts += Wo[oo] * bv[oo];
            bias[256] = ts;
        }
    } else {
        val = 0;
        if (c == 0) bias[o] = 0.f;
    }
    const int mt = o >> 4, l16 = o & 15;
    const int kk = c >> 5, g = (c >> 3) & 3, e = c & 7;
    Wt[(size_t)((mt * 8 + kk) * 64 + g * 16 + l16) * 8 + e] = val;
}

// k1: MFMA GEMM (r13 structure). Epilogue now writes CHUNKED layout:
// qkc[chunk][px][32q|32k] u16 so k2's window staging is fully coalesced.
// D map: col(px)=l&15, row=(l>>4)*4+r (m89).
__global__ __launch_bounds__(512) void k1_proj(
    const float* __restrict__ x, const u16* __restrict__ Wt,
    const float* __restrict__ bias,
    u16* __restrict__ qkc, float* __restrict__ vs) {
    __shared__ u16 xs[16][272];
    const int t = threadIdx.x;
    const int l = t & 63;
    const int w = t >> 6;
    const int lane16 = l & 15;
    const int g = l >> 4;
    const int p0 = blockIdx.x * 16;
    const int b = p0 >> 12;
    const int pin = p0 & 4095;

    const int mts[3] = {2 * w, 2 * w + 1, 16};

    u32x4 afr[8][3];
    #pragma unroll
    for (int n = 0; n < 3; ++n) {
        const u16* pA = Wt + ((size_t)(mts[n] * 8) * 64 + l) * 8;
        const u16* pB = pA + 4 * 64 * 8;
        GLD(afr[0][n], pA, "0");    GLD(afr[1][n], pA, "1024");
        GLD(afr[2][n], pA, "2048"); GLD(afr[3][n], pA, "3072");
        GLD(afr[4][n], pB, "0");    GLD(afr[5][n], pB, "1024");
        GLD(afr[6][n], pB, "2048"); GLD(afr[7][n], pB, "3072");
    }

    {   // stage x
        const int spx = t & 15, cg = t >> 4;
        const float* src = x + (size_t)(b * C_ + cg * 8) * NPB_ + pin + spx;
        float v[8];
        #pragma unroll
        for (int i = 0; i < 8; ++i) v[i] = src[(size_t)i * NPB_];
        uint4 pk;
        pk.x = (u32)f2bf(v[0]) | ((u32)f2bf(v[1]) << 16);
        pk.y = (u32)f2bf(v[2]) | ((u32)f2bf(v[3]) << 16);
        pk.z = (u32)f2bf(v[4]) | ((u32)f2bf(v[5]) << 16);
        pk.w = (u32)f2bf(v[6]) | ((u32)f2bf(v[7]) << 16);
        *reinterpret_cast<uint4*>(&xs[spx][cg * 8]) = pk;
    }
    __syncthreads();
    asm volatile("s_waitcnt vmcnt(0)" ::: "memory");
    __builtin_amdgcn_sched_barrier(0);

    f32x4_t acc[3];
    #pragma unroll
    for (int n = 0; n < 3; ++n)
        #pragma unroll
        for (int r = 0; r < 4; ++r)
            acc[n][r] = bias[mts[n] * 16 + g * 4 + r];

    #pragma unroll
    for (int kk = 0; kk < 8; ++kk) {
        const bf16x8_t bv = *reinterpret_cast<const bf16x8_t*>(&xs[lane16][kk * 32 + g * 8]);
        #pragma unroll
        for (int n = 0; n < 3; ++n) {
            const bf16x8_t av = __builtin_bit_cast(bf16x8_t, afr[kk][n]);
            acc[n] = __builtin_amdgcn_mfma_f32_16x16x32_bf16(av, bv, acc[n], 0, 0, 0);
        }
    }

    // epilogue: chunked layout
    const int px = p0 + lane16;
    #pragma unroll
    for (int n = 0; n < 2; ++n) {
        const int mt = mts[n];
        const u32 lo_ = (u32)f2bf(acc[n][0]) | ((u32)f2bf(acc[n][1]) << 16);
        const u32 hi_ = (u32)f2bf(acc[n][2]) | ((u32)f2bf(acc[n][3]) << 16);
        int chunk, base;
        if (mt < 8) { chunk = mt >> 1; base = (mt & 1) * 16 + g * 4; }
        else { const int m8 = mt - 8; chunk = m8 >> 1; base = 32 + (m8 & 1) * 16 + g * 4; }
        u32* dst = reinterpret_cast<u32*>(qkc + ((size_t)(chunk * NP_ + px)) * 64 + base);
        dst[0] = lo_; dst[1] = hi_;
    }
    if (w == 0 && g == 0) vs[px] = acc[2][0];
}

// k2 (LDS-staged tile gather): block = 4x8 px tile. Fixed 16x20 halo window
// (margin 6 >= data max |offset| ~4.8; exact global fallback otherwise) staged
// in 4 chunks of (q32|k32) ch. Scattered reads now hit LDS, not L2. Per-wave
// compute core and softmax identical to the verified r9 kernel: lane(tap,g);
// A/B share (lane,elem)->k map (HW k-perm cancels); C/D col=l&15,
// row=(l>>4)*4+reg (m89); acc chains over chunks (K-loop).
__global__ __launch_bounds__(256) void k2_attn(
    const float* __restrict__ off, const u16* __restrict__ qkc,
    const float* __restrict__ vs, const float* __restrict__ bo,
    float* __restrict__ out) {
    __shared__ u16 cb[WPX_ * CROW_];        // 43.5 KB chunk buffer
    __shared__ u32 geo[32][9][8];           // per (px,tap): 4x{idx16|gpix16, wgt}
    __shared__ float vsl[WPX_];

    const int t = threadIdx.x;
    const int l = t & 63;
    const int w = t >> 6;
    const int bid = blockIdx.x;
    const int tid = (bid & 7) * 64 + (bid >> 3);   // XCD-contiguous (512 % 8 == 0)
    const int b = tid >> 7;
    const int rr = tid & 127;
    const int ty0 = (rr >> 3) * TH_;
    const int tx0 = (rr & 7) * TW_;
    const int y0w = min(max(ty0 - 6, 0), H_ - WH_);
    const int x0w = min(max(tx0 - 6, 0), W_ - WW_);

    // ---- pre-pass: vs window + geometry ----
    for (int i = t; i < WPX_; i += 256) {
        const int gy = y0w + i / WW_, gx = x0w + i % WW_;
        vsl[i] = vs[(b << 12) + gy * W_ + gx];
    }
    for (int e = t; e < 32 * K_; e += 256) {
        const int px = e / K_, tap = e - px * K_;
        const int y = ty0 + (px >> 3), x = tx0 + (px & 7);
        const int rem = y * W_ + x;
        const float* offb = off + ((size_t)b * (2 * K_) + 2 * tap) * NPB_ + rem;
        const float oy = offb[0], ox = offb[NPB_];
        const float pyf = (float)(y + tap / 3 - 1) + oy;
        const float pxf = (float)(x + tap % 3 - 1) + ox;
        const float fy0 = floorf(pyf), fx0 = floorf(pxf);
        const float fy = pyf - fy0, fx = pxf - fx0;
        const int y0 = (int)fy0, x0 = (int)fx0;
        #pragma unroll
        for (int c = 0; c < 4; ++c) {
            const int dy = c >> 1, dx = c & 1;
            const int yi = y0 + dy, xi = x0 + dx;
            const float wv = (dy ? fy : 1.f - fy) * (dx ? fx : 1.f - fx);
            const int ok = (yi >= 0) & (yi < H_) & (xi >= 0) & (xi < W_);
            const int yc = min(max(yi, 0), H_ - 1);
            const int xc = min(max(xi, 0), W_ - 1);
            const int wy = yc - y0w, wx = xc - x0w;
            const int in = ((unsigned)wy < WH_) & ((unsigned)wx < WW_);
            const u32 idx = in ? (u32)(wy * WW_ + wx) : 0xFFFFu;
            union { float f; u32 i; } wb; wb.f = ok ? wv : 0.f;
            geo[px][tap][2 * c]     = (idx << 16) | (u32)(yc * W_ + xc);
            geo[px][tap][2 * c + 1] = wb.i;
        }
    }
    __syncthreads();

    const int l16 = l & 15;
    const int tap = (l16 < K_) ? l16 : (K_ - 1);
    const int g = l >> 4;

    f32x4_t acc[8];
    float vsu[8];
    #pragma unroll
    for (int ps = 0; ps < 8; ++ps) {
        acc[ps] = (f32x4_t){0.f, 0.f, 0.f, 0.f};
        vsu[ps] = 0.f;
    }

    for (int c = 0; c < 4; ++c) {
        // stage chunk c: 320 px x 128B, coalesced
        for (int i = t; i < WPX_ * 2; i += 256) {
            const int wp = i >> 1, half = i & 1;
            const int gy = y0w + wp / WW_, gx = x0w + wp % WW_;
            const u16* src = qkc + ((size_t)(c * NP_ + (b << 12) + gy * W_ + gx)) * 64 + half * 32;
            const uint4 v0 = *reinterpret_cast<const uint4*>(src);
            const uint4 v1 = *reinterpret_cast<const uint4*>(src + 8);
            const uint4 v2 = *reinterpret_cast<const uint4*>(src + 16);
            const uint4 v3 = *reinterpret_cast<const uint4*>(src + 24);
            u16* d = &cb[wp * CROW_ + half * 32];
            *reinterpret_cast<uint4*>(d) = v0;
            *reinterpret_cast<uint4*>(d + 8) = v1;
            *reinterpret_cast<uint4*>(d + 16) = v2;
            *reinterpret_cast<uint4*>(d + 24) = v3;
        }
        __syncthreads();

        #pragma unroll
        for (int ps = 0; ps < 8; ++ps) {
            const int local = w * 8 + ps;
            const u32x4 ge0 = *reinterpret_cast<const u32x4*>(&geo[local][tap][0]);
            const u32x4 ge1 = *reinterpret_cast<const u32x4*>(&geo[local][tap][4]);
            f32x2_t fq[4], fk[4];
            #pragma unroll
            for (int e = 0; e < 4; ++e) { fq[e] = (f32x2_t){0.f, 0.f}; fk[e] = (f32x2_t){0.f, 0.f}; }
            #pragma unroll
            for (int cn = 0; cn < 4; ++cn) {
                const u32 gi_w = (cn < 2) ? ge0[2 * cn] : ge1[2 * (cn - 2)];
                union { u32 i; float f; } wb;
                wb.i = (cn < 2) ? ge0[2 * cn + 1] : ge1[2 * (cn - 2) + 1];
                const float wv = wb.f;
                const u32 idx = gi_w >> 16;
                u32x4 qv, kv;
                if (idx != 0xFFFFu) {
                    const u16* p = &cb[idx * CROW_ + g * 8];
                    qv = *reinterpret_cast<const u32x4*>(p);
                    kv = *reinterpret_cast<const u32x4*>(p + 32);
                    if (c == 0) vsu[ps] += wv * vsl[idx];
                } else {   // exact fallback (|offset| > 6; ~never)
                    const u32 gp = gi_w & 0xFFFFu;
                    const u16* p = qkc + ((size_t)(c * NP_ + (b << 12) + gp)) * 64 + g * 8;
                    qv = *reinterpret_cast<const u32x4*>(p);
                    kv = *reinterpret_cast<const u32x4*>(p + 32);
                    if (c == 0) vsu[ps] += wv * vs[(b << 12) + gp];
                }
                const f32x2_t w2 = {wv, wv};
                acc8p(fq, qv, w2);
                acc8p(fk, kv, w2);
            }
            bf16x8_t av, bv;
            #pragma unroll
            for (int e = 0; e < 4; ++e) {
                av[2 * e]     = (__bf16)fk[e].x;   // A = ku (rows j)
                av[2 * e + 1] = (__bf16)fk[e].y;
                bv[2 * e]     = (__bf16)fq[e].x;   // B = qu (cols i)
                bv[2 * e + 1] = (__bf16)fq[e].y;
            }
            acc[ps] = __builtin_amdgcn_mfma_f32_16x16x32_bf16(av, bv, acc[ps], 0, 0, 0);
        }
        __syncthreads();
    }

    // ---- tail: verified r9 softmax per pixel slot ----
    const float bof = bo[0];
    #pragma unroll
    for (int ps = 0; ps < 8; ++ps) {
        const int local = w * 8 + ps;
        const int y = ty0 + (local >> 3), x = tx0 + (local & 7);
        const int rem = y * W_ + x;

        float mx = -1e30f;
        #pragma unroll
        for (int r = 0; r < 4; ++r) {
            const int j = g * 4 + r;
            if (j < K_) mx = fmaxf(mx, acc[ps][r]);
        }
        mx = fmaxf(mx, __shfl_xor(mx, 16, 64));
        mx = fmaxf(mx, __shfl_xor(mx, 32, 64));

        float vj[4];
        #pragma unroll
        for (int r = 0; r < 4; ++r) vj[r] = __shfl(vsu[ps], g * 4 + r, 64);

        float den = 0.f, num = 0.f;
        #pragma unroll
        for (int r = 0; r < 4; ++r) {
            const int j = g * 4 + r;
            if (j < K_) {
                const float e = __expf(acc[ps][r] - mx);
                den += e;
                num += e * vj[r];
            }
        }
        den += __shfl_xor(den, 16, 64); den += __shfl_xor(den, 32, 64);
        num += __shfl_xor(num, 16, 64); num += __shfl_xor(num, 32, 64);

        if (l < K_) {
            const float z = num / den + bof;
            out[(size_t)b * K_ * NPB_ + (size_t)l * NPB_ + rem] = 1.f / (1.f + __expf(-z));
        }
    }
}

extern "C" void kernel_launch(void* const* d_in, const int* in_sizes, int n_in,
                              void* d_out, int out_size, void* d_ws, size_t ws_size,
                              hipStream_t stream) {
    const float* x   = (const float*)d_in[0];
    const float* off = (const float*)d_in[1];
    const float* Wq  = (const float*)d_in[2];
    const float* bq  = (const float*)d_in[3];
    const float* Wk  = (const float*)d_in[4];
    const float* bk  = (const float*)d_in[5];
    const float* Wv  = (const float*)d_in[6];
    const float* bv  = (const float*)d_in[7];
    const float* Wo  = (const float*)d_in[8];
    const float* bo  = (const float*)d_in[9];
    float* out = (float*)d_out;

    char* ws = (char*)d_ws;
    u16*   qkc   = (u16*)(ws + 4096);                 // 4 chunks x 16384 px x 64 u16 = 8 MiB
    float* vsmap = (float*)(ws + 4096 + 8388608);     // 16384 f32
    u16*   Wt    = (u16*)(ws + 4096 + 8388608 + 65536);
    float* bias  = (float*)(ws + 4096 + 8388608 + 65536 + 139264);

    k0b_prep<<<MROWS_, 256, 0, stream>>>(Wq, bq, Wk, bk, Wv, bv, Wo, Wt, bias);
    k1_proj<<<NP_ / 16, 512, 0, stream>>>(x, Wt, bias, qkc, vsmap);
    k2_attn<<<512, 256, 0, stream>>>(off, qkc, vsmap, bo, out);
}